// Round 6
// baseline (415.744 us; speedup 1.0000x reference)
//
#include <hip/hip_runtime.h>

typedef unsigned int u32;
typedef unsigned long long u64;

#define N_PTS 480000
#define PPB   120000      // points per batch (B=4)
#define NKEY  131072      // 4 * 32^3 compact key space
#define NBLK_A 256
#define NBLK_B 256
#define NT64   7500       // N_PTS / 64
#define SLOPE 0.01f

__device__ __forceinline__ u32 bf16pack(float lo, float hi) {
    u32 a = __float_as_uint(lo), b = __float_as_uint(hi);
    a += 0x7fffu + ((a >> 16) & 1u);   // RNE
    b += 0x7fffu + ((b >> 16) & 1u);
    return (a >> 16) | (b & 0xffff0000u);
}
__device__ __forceinline__ float bf_lo(u32 v) { return __uint_as_float(v << 16); }
__device__ __forceinline__ float bf_hi(u32 v) { return __uint_as_float(v & 0xffff0000u); }

// ================= node 1: zero cnt + keys + x-moment partials =================
__global__ __launch_bounds__(256) void kA0(const float* __restrict__ pc,
                                           const int* __restrict__ pidx,
                                           u32* __restrict__ keys,
                                           u32* __restrict__ cnt,
                                           float* __restrict__ pA) {
    int t = threadIdx.x;
    int g = blockIdx.x * 256 + t;
    ((u64*)cnt)[g] = 0ull;            // 65536 threads x 8B = 512KB, exact

    float a[14];
#pragma unroll
    for (int j = 0; j < 14; ++j) a[j] = 0.f;

    for (int n = g; n < N_PTS; n += NBLK_A * 256) {
        float4 x = ((const float4*)pc)[n];
        a[0] += x.x; a[1] += x.y; a[2] += x.z; a[3] += x.w;
        a[4] += x.x * x.x; a[5] += x.x * x.y; a[6]  += x.x * x.z; a[7]  += x.x * x.w;
        a[8] += x.y * x.y; a[9] += x.y * x.z; a[10] += x.y * x.w;
        a[11] += x.z * x.z; a[12] += x.z * x.w; a[13] += x.w * x.w;

        int i0 = pidx[3 * n], i1 = pidx[3 * n + 1], i2 = pidx[3 * n + 2];
        int bid = n / PPB;
        keys[n] = (u32)(bid * 32768 + i0 * 1024 + i1 * 32 + i2);
    }

    __shared__ float red[256];
    for (int j = 0; j < 14; ++j) {
        red[t] = a[j];
        __syncthreads();
        for (int s = 128; s > 0; s >>= 1) {
            if (t < s) red[t] += red[t + s];
            __syncthreads();
        }
        if (t == 0) pA[j * NBLK_A + blockIdx.x] = red[0];   // moment-major
        __syncthreads();
    }
}

// ================= node 2: fold1 (per block) + histogram + h-moments =================
__global__ __launch_bounds__(256, 1) void kB(const float* __restrict__ pc,
                                             const u32* __restrict__ keys,
                                             const float* __restrict__ pA,
                                             const float* __restrict__ W1,
                                             const float* __restrict__ b1,
                                             const float* __restrict__ g1,
                                             const float* __restrict__ be1,
                                             u32* __restrict__ cnt,
                                             float* __restrict__ pB,
                                             float* __restrict__ stats1) {
    int t = threadIdx.x, w = t >> 6, lane = t & 63;
    __shared__ float S[14];
    __shared__ float sW[80];
    __shared__ float sred[4][152];

    // fold1: reduce pA (every block, redundantly -- kills a launch)
    for (int q = w; q < 14; q += 4) {
        const float* p = pA + q * NBLK_A;
        float s = p[lane] + p[lane + 64] + p[lane + 128] + p[lane + 192];
        for (int d = 32; d > 0; d >>= 1) s += __shfl_xor(s, d);
        if (lane == 0) S[q] = s;
    }
    __syncthreads();
    if (t < 16) {
        int c = t;
        double w4[4];
#pragma unroll
        for (int i = 0; i < 4; ++i) w4[i] = W1[i * 16 + c];
        double sx[4] = { S[0], S[1], S[2], S[3] };
        auto sxx = [&](int i, int j) -> double {
            if (i > j) { int k = i; i = j; j = k; }
            int base = (i == 0) ? 4 : (i == 1) ? 8 : (i == 2) ? 11 : 13;
            return (double)S[base + (j - i)];
        };
        double su = 0.0;
        for (int i = 0; i < 4; ++i) su += sx[i] * w4[i];
        double q = 0.0;
        for (int i = 0; i < 4; ++i)
            for (int j = 0; j < 4; ++j) q += w4[i] * w4[j] * sxx(i, j);
        double b = (double)b1[c];
        double sum   = su + b * (double)N_PTS;
        double sumsq = q + 2.0 * b * su + (double)N_PTS * b * b;
        double mean = sum / (double)N_PTS;
        double var  = sumsq / (double)N_PTS - mean * mean;
        float inv = rsqrtf((float)(var + 1e-5));
        float sc = g1[c] * inv;
        float sf = be1[c] - (float)mean * sc;
#pragma unroll
        for (int i = 0; i < 4; ++i) sW[c * 4 + i] = W1[i * 16 + c] * sc;
        sW[64 + c] = b1[c] * sc + sf;
        if (blockIdx.x == 0) {
#pragma unroll
            for (int i = 0; i < 4; ++i) stats1[c * 4 + i] = sW[c * 4 + i];
            stats1[64 + c] = sW[64 + c];
        }
    }
    __syncthreads();

    // histogram (cnt zeroed by node 1)
    for (int n = blockIdx.x * 256 + t; n < N_PTS; n += NBLK_B * 256)
        atomicAdd(&cnt[keys[n]], 1u);

    // h-moments in registers
    float acc[152];
#pragma unroll
    for (int m = 0; m < 152; ++m) acc[m] = 0.f;

    const float4* sW4 = (const float4*)sW;
    for (int n = blockIdx.x * 256 + t; n < N_PTS; n += NBLK_B * 256) {
        float4 x = ((const float4*)pc)[n];
        float h[16];
#pragma unroll
        for (int k = 0; k < 16; ++k) {
            float4 wk = sW4[k];
            float z = x.x * wk.x + x.y * wk.y + x.z * wk.z + x.w * wk.w + sW[64 + k];
            h[k] = (z >= 0.f) ? z : SLOPE * z;
        }
#pragma unroll
        for (int i = 0; i < 16; ++i) acc[i] += h[i];
#pragma unroll
        for (int i = 0; i < 16; ++i)
#pragma unroll
            for (int j = i; j < 16; ++j)
                acc[16 + i * 16 - (i * (i - 1)) / 2 + (j - i)] += h[i] * h[j];
    }

#pragma unroll
    for (int m = 0; m < 152; ++m) {
        float s = acc[m];
        for (int d = 32; d > 0; d >>= 1) s += __shfl_xor(s, d);
        acc[m] = s;
    }
    if (lane == 0) {
#pragma unroll
        for (int m = 0; m < 152; ++m) sred[w][m] = acc[m];
    }
    __syncthreads();
    if (t < 152)
        pB[t * NBLK_B + blockIdx.x] = sred[0][t] + sred[1][t] + sred[2][t] + sred[3][t];
}

// ================= node 3: fold2 + full scan (1 block, 1024 threads) =================
__global__ __launch_bounds__(1024) void kMid(const float* __restrict__ pB,
                                             const float* __restrict__ W2,
                                             const float* __restrict__ b2,
                                             const float* __restrict__ g2,
                                             const float* __restrict__ be2,
                                             float* __restrict__ stats2,
                                             u32* cnt,               // read then overwritten (cursor)
                                             u32* __restrict__ startc,
                                             float* __restrict__ vi,
                                             u32* __restrict__ nuni) {
    int t = threadIdx.x, w = t >> 6, lane = t & 63;
    __shared__ float S[152];
    __shared__ u64 sc[1024];

    // ---- fold2 ----
    for (int q = w; q < 152; q += 16) {
        const float* p = pB + q * NBLK_B;
        float s = p[lane] + p[lane + 64] + p[lane + 128] + p[lane + 192];
        for (int d = 32; d > 0; d >>= 1) s += __shfl_xor(s, d);
        if (lane == 0) S[q] = s;
    }
    __syncthreads();
    if (t < 64) {
        double wv[16];
#pragma unroll
        for (int k = 0; k < 16; ++k) wv[k] = W2[k * 64 + t];
        double sh = 0.0;
        for (int k = 0; k < 16; ++k) sh += wv[k] * (double)S[k];
        auto qidx = [&](int i, int j) { return 16 + i * 16 - (i * (i - 1)) / 2 + (j - i); };
        double q = 0.0;
        for (int i = 0; i < 16; ++i) {
            q += wv[i] * wv[i] * (double)S[qidx(i, i)];
            double t2 = 0.0;
            for (int j = i + 1; j < 16; ++j) t2 += wv[j] * (double)S[qidx(i, j)];
            q += 2.0 * wv[i] * t2;
        }
        double b = (double)b2[t];
        double sum   = sh + b * (double)N_PTS;
        double sumsq = q + 2.0 * b * sh + (double)N_PTS * b * b;
        double mean = sum / (double)N_PTS;
        double var  = sumsq / (double)N_PTS - mean * mean;
        float inv = rsqrtf((float)(var + 1e-5));
        float scs = g2[t] * inv;
        float sf = be2[t] - (float)mean * scs;
#pragma unroll
        for (int k = 0; k < 16; ++k) stats2[k * 64 + t] = W2[k * 64 + t] * scs;
        stats2[1024 + t] = b2[t] * scs + sf;
    }
    __syncthreads();

    // ---- scan: thread t owns keys [128t, 128t+128) ----
    const uint4* c4 = (const uint4*)cnt;
    int base4 = t * 32;
    u32 ls = 0, lo = 0;
    for (int j = 0; j < 32; ++j) {
        uint4 v = c4[base4 + j];
        ls += v.x + v.y + v.z + v.w;
        lo += (v.x > 0) + (v.y > 0) + (v.z > 0) + (v.w > 0);
    }
    u64 mine = ((u64)ls << 32) | (u64)lo;
    sc[t] = mine;
    __syncthreads();
    for (int d = 1; d < 1024; d <<= 1) {
        u64 v = (t >= d) ? sc[t - d] : 0ull;
        __syncthreads();
        sc[t] += v;
        __syncthreads();
    }
    u64 ex = sc[t] - mine;
    u32 start = (u32)(ex >> 32);
    u32 rank  = (u32)(ex & 0xffffffffull);

    for (int j = 0; j < 32; ++j) {
        uint4 v = c4[base4 + j];        // read before overwriting same 16B below
        u32 k0 = (u32)(base4 + j) * 4;
        u32 cv[4] = { v.x, v.y, v.z, v.w };
#pragma unroll
        for (int e = 0; e < 4; ++e) {
            u32 k = k0 + e;
            cnt[k] = start;             // cursor
            if (cv[e] > 0) {
                startc[rank] = start;
                float4 o;
                o.x = (float)(k >> 15);
                o.y = (float)((k >> 10) & 31);
                o.z = (float)((k >> 5) & 31);
                o.w = (float)(k & 31);
                ((float4*)vi)[rank] = o;
                rank++;
            }
            start += cv[e];
        }
    }
    if (t == 1023) {
        nuni[0] = rank;
        startc[rank] = N_PTS;           // sentinel
    }
}

// ================= node 4: pid scatter + MLP -> feat =================
__global__ __launch_bounds__(256) void kC(const float* __restrict__ pc,
                                          const u32* __restrict__ keys,
                                          u32* __restrict__ cursor,
                                          u32* __restrict__ pid,
                                          const float* __restrict__ stats1,
                                          const float* __restrict__ stats2,
                                          float* __restrict__ feat_out) {
    int t = threadIdx.x;

    // scatter phase (no sync needed vs MLP phase; independent buffers)
    for (int n = blockIdx.x * 256 + t; n < N_PTS; n += 2048 * 256) {
        u32 k = keys[n];
        u32 pos = atomicAdd(&cursor[k], 1u);
        pid[pos] = (u32)n;
    }

    __shared__ u32 shp[64][8];     // h as bf16 pairs

    int cpair = t & 7, psub = t >> 3;
    float w1a[4], w1b[4], c1a, c1b;
#pragma unroll
    for (int i = 0; i < 4; ++i) {
        w1a[i] = stats1[(2 * cpair) * 4 + i];
        w1b[i] = stats1[(2 * cpair + 1) * 4 + i];
    }
    c1a = stats1[64 + 2 * cpair];
    c1b = stats1[64 + 2 * cpair + 1];

    int c2 = t & 63, pg = t >> 6;
    float w2c[16];
#pragma unroll
    for (int k = 0; k < 16; ++k) w2c[k] = stats2[k * 64 + c2];
    float c2fr = stats2[1024 + c2];

    for (int tile = blockIdx.x; tile < NT64; tile += 2048) {
        int base = tile * 64;
#pragma unroll
        for (int half = 0; half < 2; ++half) {
            int p = psub + 32 * half;
            float4 x = ((const float4*)pc)[base + p];
            float za = x.x * w1a[0] + x.y * w1a[1] + x.z * w1a[2] + x.w * w1a[3] + c1a;
            float zb = x.x * w1b[0] + x.y * w1b[1] + x.z * w1b[2] + x.w * w1b[3] + c1b;
            za = (za >= 0.f) ? za : SLOPE * za;
            zb = (zb >= 0.f) ? zb : SLOPE * zb;
            shp[p][cpair] = bf16pack(za, zb);
        }
        __syncthreads();
#pragma unroll
        for (int j = 0; j < 16; ++j) {
            int p = pg + 4 * j;
            const uint4* row = (const uint4*)&shp[p][0];
            uint4 v0 = row[0], v1 = row[1];
            float f = c2fr;
            f += bf_lo(v0.x) * w2c[0]  + bf_hi(v0.x) * w2c[1];
            f += bf_lo(v0.y) * w2c[2]  + bf_hi(v0.y) * w2c[3];
            f += bf_lo(v0.z) * w2c[4]  + bf_hi(v0.z) * w2c[5];
            f += bf_lo(v0.w) * w2c[6]  + bf_hi(v0.w) * w2c[7];
            f += bf_lo(v1.x) * w2c[8]  + bf_hi(v1.x) * w2c[9];
            f += bf_lo(v1.y) * w2c[10] + bf_hi(v1.y) * w2c[11];
            f += bf_lo(v1.z) * w2c[12] + bf_hi(v1.z) * w2c[13];
            f += bf_lo(v1.w) * w2c[14] + bf_hi(v1.w) * w2c[15];
            float ff = (f >= 0.f) ? f : SLOPE * f;
            feat_out[(size_t)(base + p) * 64 + c2] = ff;
        }
        __syncthreads();
    }
}

// ================= node 5: gather-max per voxel; zero tails (grid-stride) =================
__global__ __launch_bounds__(256) void kV(const float* __restrict__ feat,
                                          const u32* __restrict__ pid,
                                          const u32* __restrict__ startc,
                                          const u32* __restrict__ nuni,
                                          float* __restrict__ vf,
                                          float* __restrict__ vi) {
    u32 nu = *nuni;
    int w = threadIdx.x >> 6, lane = threadIdx.x & 63;
    for (u32 r = blockIdx.x * 4 + (u32)w; r < N_PTS; r += 8192) {
        if (r < nu) {
            u32 s = startc[r], e = startc[r + 1];
            float m = -3.4e38f;
            for (u32 i = s; i < e; ++i) {
                u32 p = pid[i];
                m = fmaxf(m, feat[(size_t)p * 64 + lane]);
            }
            vf[(size_t)r * 64 + lane] = m;
        } else {
            vf[(size_t)r * 64 + lane] = 0.f;
            if (lane < 4) vi[(size_t)r * 4 + lane] = 0.f;
        }
    }
}

extern "C" void kernel_launch(void* const* d_in, const int* in_sizes, int n_in,
                              void* d_out, int out_size, void* d_ws, size_t ws_size,
                              hipStream_t stream) {
    const float* pc   = (const float*)d_in[0];
    const int*   pidx = (const int*)d_in[1];
    const float* W1   = (const float*)d_in[2];
    const float* b1   = (const float*)d_in[3];
    const float* g1   = (const float*)d_in[4];
    const float* be1  = (const float*)d_in[5];
    const float* W2   = (const float*)d_in[6];
    const float* b2   = (const float*)d_in[7];
    const float* g2   = (const float*)d_in[8];
    const float* be2  = (const float*)d_in[9];

    float* vf   = (float*)d_out;                    // [N,64]
    float* vi   = vf + (size_t)N_PTS * 64;          // [N,4]
    float* feat = vi + (size_t)N_PTS * 4;           // [N,64]

    u32* ws     = (u32*)d_ws;
    u32* keys   = ws;                        // 480000
    u32* cnt    = ws + 480000;               // 131072 (count -> cursor)
    u32* startc = ws + 611072;               // 131073 (+pad)
    u32* nuni   = ws + 742148;               // 1 (+pad)
    u32* pid    = ws + 742164;               // 480000
    float* pA     = (float*)(ws + 1222164);  // 14*256 = 3584
    float* stats1 = (float*)(ws + 1225748);  // 80
    float* pB     = (float*)(ws + 1225828);  // 152*256 = 38912
    float* stats2 = (float*)(ws + 1264740);  // 1088

    kA0<<<NBLK_A, 256, 0, stream>>>(pc, pidx, keys, cnt, pA);
    kB<<<NBLK_B, 256, 0, stream>>>(pc, keys, pA, W1, b1, g1, be1, cnt, pB, stats1);
    kMid<<<1, 1024, 0, stream>>>(pB, W2, b2, g2, be2, stats2, cnt, startc, vi, nuni);
    kC<<<2048, 256, 0, stream>>>(pc, keys, cnt, pid, stats1, stats2, feat);
    kV<<<2048, 256, 0, stream>>>(feat, pid, startc, nuni, vf, vi);
}

// Round 7
// 195.568 us; speedup vs baseline: 2.1258x; 2.1258x over previous
//
#include <hip/hip_runtime.h>

typedef unsigned int u32;
typedef unsigned long long u64;

#define N_PTS 480000
#define PPB   120000      // points per batch (B=4)
#define NKEY  131072      // 4 * 32^3 compact key space
#define NBLK_A 256
#define NBLK_B 256
#define NT64   7500       // N_PTS / 64
#define SLOPE 0.01f

__device__ __forceinline__ u32 bf16pack(float lo, float hi) {
    u32 a = __float_as_uint(lo), b = __float_as_uint(hi);
    a += 0x7fffu + ((a >> 16) & 1u);   // RNE
    b += 0x7fffu + ((b >> 16) & 1u);
    return (a >> 16) | (b & 0xffff0000u);
}
__device__ __forceinline__ float bf_lo(u32 v) { return __uint_as_float(v << 16); }
__device__ __forceinline__ float bf_hi(u32 v) { return __uint_as_float(v & 0xffff0000u); }

// ================= node 1: zero cnt + keys + x-moment partials =================
__global__ __launch_bounds__(256) void kA0(const float* __restrict__ pc,
                                           const int* __restrict__ pidx,
                                           u32* __restrict__ keys,
                                           u32* __restrict__ cnt,
                                           float* __restrict__ pA) {
    int t = threadIdx.x;
    int g = blockIdx.x * 256 + t;
    ((u64*)cnt)[g] = 0ull;            // 65536 threads x 8B = 512KB, exact

    float a[14];
#pragma unroll
    for (int j = 0; j < 14; ++j) a[j] = 0.f;

    for (int n = g; n < N_PTS; n += NBLK_A * 256) {
        float4 x = ((const float4*)pc)[n];
        a[0] += x.x; a[1] += x.y; a[2] += x.z; a[3] += x.w;
        a[4] += x.x * x.x; a[5] += x.x * x.y; a[6]  += x.x * x.z; a[7]  += x.x * x.w;
        a[8] += x.y * x.y; a[9] += x.y * x.z; a[10] += x.y * x.w;
        a[11] += x.z * x.z; a[12] += x.z * x.w; a[13] += x.w * x.w;

        int i0 = pidx[3 * n], i1 = pidx[3 * n + 1], i2 = pidx[3 * n + 2];
        int bid = n / PPB;
        keys[n] = (u32)(bid * 32768 + i0 * 1024 + i1 * 32 + i2);
    }

    __shared__ float red[256];
    for (int j = 0; j < 14; ++j) {
        red[t] = a[j];
        __syncthreads();
        for (int s = 128; s > 0; s >>= 1) {
            if (t < s) red[t] += red[t + s];
            __syncthreads();
        }
        if (t == 0) pA[j * NBLK_A + blockIdx.x] = red[0];   // moment-major
        __syncthreads();
    }
}

// ================= node 2: fold1 (per block) + histogram + h-moments =================
__global__ __launch_bounds__(256, 1) void kB(const float* __restrict__ pc,
                                             const u32* __restrict__ keys,
                                             const float* __restrict__ pA,
                                             const float* __restrict__ W1,
                                             const float* __restrict__ b1,
                                             const float* __restrict__ g1,
                                             const float* __restrict__ be1,
                                             u32* __restrict__ cnt,
                                             float* __restrict__ pB,
                                             float* __restrict__ stats1) {
    int t = threadIdx.x, w = t >> 6, lane = t & 63;
    __shared__ float S[14];
    __shared__ float sW[80];
    __shared__ float sred[4][152];

    // fold1: reduce pA (every block, redundantly -- kills a launch)
    for (int q = w; q < 14; q += 4) {
        const float* p = pA + q * NBLK_A;
        float s = p[lane] + p[lane + 64] + p[lane + 128] + p[lane + 192];
        for (int d = 32; d > 0; d >>= 1) s += __shfl_xor(s, d);
        if (lane == 0) S[q] = s;
    }
    __syncthreads();
    if (t < 16) {
        int c = t;
        double w4[4];
#pragma unroll
        for (int i = 0; i < 4; ++i) w4[i] = W1[i * 16 + c];
        double sx[4] = { S[0], S[1], S[2], S[3] };
        auto sxx = [&](int i, int j) -> double {
            if (i > j) { int k = i; i = j; j = k; }
            int base = (i == 0) ? 4 : (i == 1) ? 8 : (i == 2) ? 11 : 13;
            return (double)S[base + (j - i)];
        };
        double su = 0.0;
        for (int i = 0; i < 4; ++i) su += sx[i] * w4[i];
        double q = 0.0;
        for (int i = 0; i < 4; ++i)
            for (int j = 0; j < 4; ++j) q += w4[i] * w4[j] * sxx(i, j);
        double b = (double)b1[c];
        double sum   = su + b * (double)N_PTS;
        double sumsq = q + 2.0 * b * su + (double)N_PTS * b * b;
        double mean = sum / (double)N_PTS;
        double var  = sumsq / (double)N_PTS - mean * mean;
        float inv = rsqrtf((float)(var + 1e-5));
        float sc = g1[c] * inv;
        float sf = be1[c] - (float)mean * sc;
#pragma unroll
        for (int i = 0; i < 4; ++i) sW[c * 4 + i] = W1[i * 16 + c] * sc;
        sW[64 + c] = b1[c] * sc + sf;
        if (blockIdx.x == 0) {
#pragma unroll
            for (int i = 0; i < 4; ++i) stats1[c * 4 + i] = sW[c * 4 + i];
            stats1[64 + c] = sW[64 + c];
        }
    }
    __syncthreads();

    // histogram (cnt zeroed by node 1)
    for (int n = blockIdx.x * 256 + t; n < N_PTS; n += NBLK_B * 256)
        atomicAdd(&cnt[keys[n]], 1u);

    // h-moments in registers
    float acc[152];
#pragma unroll
    for (int m = 0; m < 152; ++m) acc[m] = 0.f;

    const float4* sW4 = (const float4*)sW;
    for (int n = blockIdx.x * 256 + t; n < N_PTS; n += NBLK_B * 256) {
        float4 x = ((const float4*)pc)[n];
        float h[16];
#pragma unroll
        for (int k = 0; k < 16; ++k) {
            float4 wk = sW4[k];
            float z = x.x * wk.x + x.y * wk.y + x.z * wk.z + x.w * wk.w + sW[64 + k];
            h[k] = (z >= 0.f) ? z : SLOPE * z;
        }
#pragma unroll
        for (int i = 0; i < 16; ++i) acc[i] += h[i];
#pragma unroll
        for (int i = 0; i < 16; ++i)
#pragma unroll
            for (int j = i; j < 16; ++j)
                acc[16 + i * 16 - (i * (i - 1)) / 2 + (j - i)] += h[i] * h[j];
    }

#pragma unroll
    for (int m = 0; m < 152; ++m) {
        float s = acc[m];
        for (int d = 32; d > 0; d >>= 1) s += __shfl_xor(s, d);
        acc[m] = s;
    }
    if (lane == 0) {
#pragma unroll
        for (int m = 0; m < 152; ++m) sred[w][m] = acc[m];
    }
    __syncthreads();
    if (t < 152)
        pB[t * NBLK_B + blockIdx.x] = sred[0][t] + sred[1][t] + sred[2][t] + sred[3][t];
}

// ================= node 3: scan pass 1 (128 blocks) + fold2 in block 0 =================
__global__ __launch_bounds__(256) void kS1(const u32* __restrict__ cnt,
                                           u32* __restrict__ bsum,
                                           const float* __restrict__ pB,
                                           const float* __restrict__ W2,
                                           const float* __restrict__ b2,
                                           const float* __restrict__ g2,
                                           const float* __restrict__ be2,
                                           float* __restrict__ stats2) {
    int t = threadIdx.x, b = blockIdx.x;
    uint4 c4 = ((const uint4*)cnt)[b * 256 + t];
    u32 cs = c4.x + c4.y + c4.z + c4.w;
    u32 os = (c4.x > 0) + (c4.y > 0) + (c4.z > 0) + (c4.w > 0);
    __shared__ u32 rc[256], ro[256];
    rc[t] = cs; ro[t] = os;
    __syncthreads();
    for (int s = 128; s > 0; s >>= 1) {
        if (t < s) { rc[t] += rc[t + s]; ro[t] += ro[t + s]; }
        __syncthreads();
    }
    if (t == 0) { bsum[2 * b] = rc[0]; bsum[2 * b + 1] = ro[0]; }

    if (b == 0) {
        // fold2: reduce pB -> S[152], then stats2
        int w = t >> 6, lane = t & 63;
        __shared__ float S[152];
        for (int q = w; q < 152; q += 4) {
            const float* p = pB + q * NBLK_B;
            float s = p[lane] + p[lane + 64] + p[lane + 128] + p[lane + 192];
            for (int d = 32; d > 0; d >>= 1) s += __shfl_xor(s, d);
            if (lane == 0) S[q] = s;
        }
        __syncthreads();
        if (t < 64) {
            double wv[16];
#pragma unroll
            for (int k = 0; k < 16; ++k) wv[k] = W2[k * 64 + t];
            double sh = 0.0;
            for (int k = 0; k < 16; ++k) sh += wv[k] * (double)S[k];
            auto qidx = [&](int i, int j) { return 16 + i * 16 - (i * (i - 1)) / 2 + (j - i); };
            double q = 0.0;
            for (int i = 0; i < 16; ++i) {
                q += wv[i] * wv[i] * (double)S[qidx(i, i)];
                double t2 = 0.0;
                for (int j = i + 1; j < 16; ++j) t2 += wv[j] * (double)S[qidx(i, j)];
                q += 2.0 * wv[i] * t2;
            }
            double bb = (double)b2[t];
            double sum   = sh + bb * (double)N_PTS;
            double sumsq = q + 2.0 * bb * sh + (double)N_PTS * bb * bb;
            double mean = sum / (double)N_PTS;
            double var  = sumsq / (double)N_PTS - mean * mean;
            float inv = rsqrtf((float)(var + 1e-5));
            float scs = g2[t] * inv;
            float sf = be2[t] - (float)mean * scs;
#pragma unroll
            for (int k = 0; k < 16; ++k) stats2[k * 64 + t] = W2[k * 64 + t] * scs;
            stats2[1024 + t] = b2[t] * scs + sf;
        }
    }
}

// ================= node 4: scan pass 2: cursors, startc, vi rows, n_uni =================
__global__ __launch_bounds__(256) void kS2(u32* __restrict__ cnt,
                                           const u32* __restrict__ bsum,
                                           u32* __restrict__ startc,
                                           float* __restrict__ vi,
                                           u32* __restrict__ nuni) {
    int t = threadIdx.x, b = blockIdx.x;
    __shared__ u32 sbc[128], sbo[128];
    __shared__ u32 cOff, oOff;
    __shared__ u64 scan[256];
    if (t < 128) { sbc[t] = bsum[2 * t]; sbo[t] = bsum[2 * t + 1]; }

    uint4 c4 = ((const uint4*)cnt)[b * 256 + t];
    u32 cv[4] = { c4.x, c4.y, c4.z, c4.w };
    u32 cs = cv[0] + cv[1] + cv[2] + cv[3];
    u32 os = (cv[0] > 0) + (cv[1] > 0) + (cv[2] > 0) + (cv[3] > 0);
    scan[t] = ((u64)cs << 32) | (u64)os;
    __syncthreads();
    if (t == 0) {
        u32 a = 0, o = 0;
        for (int i = 0; i < b; ++i) { a += sbc[i]; o += sbo[i]; }
        cOff = a; oOff = o;
    }
    for (int d = 1; d < 256; d <<= 1) {
        u64 v = (t >= d) ? scan[t - d] : 0ull;
        __syncthreads();
        scan[t] += v;
        __syncthreads();
    }
    u64 ex = scan[t] - (((u64)cs << 32) | (u64)os);
    u32 start = cOff + (u32)(ex >> 32);
    u32 rank  = oOff + (u32)(ex & 0xffffffffull);

    int kbase = b * 1024 + t * 4;
#pragma unroll
    for (int j = 0; j < 4; ++j) {
        u32 k = (u32)(kbase + j);
        cnt[k] = start;                     // cursor
        if (cv[j] > 0) {
            startc[rank] = start;
            float4 o;
            o.x = (float)(k >> 15);
            o.y = (float)((k >> 10) & 31);
            o.z = (float)((k >> 5) & 31);
            o.w = (float)(k & 31);
            ((float4*)vi)[rank] = o;
            rank++;
        }
        start += cv[j];
    }
    if (b == 127 && t == 255) {
        nuni[0] = rank;
        startc[rank] = N_PTS;               // sentinel
    }
}

// ================= node 5: pid scatter + MLP -> feat =================
__global__ __launch_bounds__(256) void kC(const float* __restrict__ pc,
                                          const u32* __restrict__ keys,
                                          u32* __restrict__ cursor,
                                          u32* __restrict__ pid,
                                          const float* __restrict__ stats1,
                                          const float* __restrict__ stats2,
                                          float* __restrict__ feat_out) {
    int t = threadIdx.x;

    // scatter phase
    for (int n = blockIdx.x * 256 + t; n < N_PTS; n += 2048 * 256) {
        u32 k = keys[n];
        u32 pos = atomicAdd(&cursor[k], 1u);
        pid[pos] = (u32)n;
    }

    __shared__ u32 shp[64][8];     // h as bf16 pairs

    int cpair = t & 7, psub = t >> 3;
    float w1a[4], w1b[4], c1a, c1b;
#pragma unroll
    for (int i = 0; i < 4; ++i) {
        w1a[i] = stats1[(2 * cpair) * 4 + i];
        w1b[i] = stats1[(2 * cpair + 1) * 4 + i];
    }
    c1a = stats1[64 + 2 * cpair];
    c1b = stats1[64 + 2 * cpair + 1];

    int c2 = t & 63, pg = t >> 6;
    float w2c[16];
#pragma unroll
    for (int k = 0; k < 16; ++k) w2c[k] = stats2[k * 64 + c2];
    float c2fr = stats2[1024 + c2];

    for (int tile = blockIdx.x; tile < NT64; tile += 2048) {
        int base = tile * 64;
#pragma unroll
        for (int half = 0; half < 2; ++half) {
            int p = psub + 32 * half;
            float4 x = ((const float4*)pc)[base + p];
            float za = x.x * w1a[0] + x.y * w1a[1] + x.z * w1a[2] + x.w * w1a[3] + c1a;
            float zb = x.x * w1b[0] + x.y * w1b[1] + x.z * w1b[2] + x.w * w1b[3] + c1b;
            za = (za >= 0.f) ? za : SLOPE * za;
            zb = (zb >= 0.f) ? zb : SLOPE * zb;
            shp[p][cpair] = bf16pack(za, zb);
        }
        __syncthreads();
#pragma unroll
        for (int j = 0; j < 16; ++j) {
            int p = pg + 4 * j;
            const uint4* row = (const uint4*)&shp[p][0];
            uint4 v0 = row[0], v1 = row[1];
            float f = c2fr;
            f += bf_lo(v0.x) * w2c[0]  + bf_hi(v0.x) * w2c[1];
            f += bf_lo(v0.y) * w2c[2]  + bf_hi(v0.y) * w2c[3];
            f += bf_lo(v0.z) * w2c[4]  + bf_hi(v0.z) * w2c[5];
            f += bf_lo(v0.w) * w2c[6]  + bf_hi(v0.w) * w2c[7];
            f += bf_lo(v1.x) * w2c[8]  + bf_hi(v1.x) * w2c[9];
            f += bf_lo(v1.y) * w2c[10] + bf_hi(v1.y) * w2c[11];
            f += bf_lo(v1.z) * w2c[12] + bf_hi(v1.z) * w2c[13];
            f += bf_lo(v1.w) * w2c[14] + bf_hi(v1.w) * w2c[15];
            float ff = (f >= 0.f) ? f : SLOPE * f;
            feat_out[(size_t)(base + p) * 64 + c2] = ff;
        }
        __syncthreads();
    }
}

// ================= node 6: gather-max per voxel; zero tails (grid-stride) =================
__global__ __launch_bounds__(256) void kV(const float* __restrict__ feat,
                                          const u32* __restrict__ pid,
                                          const u32* __restrict__ startc,
                                          const u32* __restrict__ nuni,
                                          float* __restrict__ vf,
                                          float* __restrict__ vi) {
    u32 nu = *nuni;
    int w = threadIdx.x >> 6, lane = threadIdx.x & 63;
    for (u32 r = blockIdx.x * 4 + (u32)w; r < N_PTS; r += 8192) {
        if (r < nu) {
            u32 s = startc[r], e = startc[r + 1];
            float m = -3.4e38f;
            for (u32 i = s; i < e; ++i) {
                u32 p = pid[i];
                m = fmaxf(m, feat[(size_t)p * 64 + lane]);
            }
            vf[(size_t)r * 64 + lane] = m;
        } else {
            vf[(size_t)r * 64 + lane] = 0.f;
            if (lane < 4) vi[(size_t)r * 4 + lane] = 0.f;
        }
    }
}

extern "C" void kernel_launch(void* const* d_in, const int* in_sizes, int n_in,
                              void* d_out, int out_size, void* d_ws, size_t ws_size,
                              hipStream_t stream) {
    const float* pc   = (const float*)d_in[0];
    const int*   pidx = (const int*)d_in[1];
    const float* W1   = (const float*)d_in[2];
    const float* b1   = (const float*)d_in[3];
    const float* g1   = (const float*)d_in[4];
    const float* be1  = (const float*)d_in[5];
    const float* W2   = (const float*)d_in[6];
    const float* b2   = (const float*)d_in[7];
    const float* g2   = (const float*)d_in[8];
    const float* be2  = (const float*)d_in[9];

    float* vf   = (float*)d_out;                    // [N,64]
    float* vi   = vf + (size_t)N_PTS * 64;          // [N,4]
    float* feat = vi + (size_t)N_PTS * 4;           // [N,64]

    u32* ws     = (u32*)d_ws;
    u32* keys   = ws;                        // 480000
    u32* cnt    = ws + 480000;               // 131072 (count -> cursor)
    u32* startc = ws + 611072;               // 131073 (+pad)
    u32* bsum   = ws + 742148;               // 256
    u32* nuni   = ws + 742404;               // 1 (+pad)
    u32* pid    = ws + 742420;               // 480000
    float* pA     = (float*)(ws + 1222420);  // 14*256 = 3584
    float* stats1 = (float*)(ws + 1226004);  // 80
    float* pB     = (float*)(ws + 1226084);  // 152*256 = 38912
    float* stats2 = (float*)(ws + 1264996);  // 1088

    kA0<<<NBLK_A, 256, 0, stream>>>(pc, pidx, keys, cnt, pA);
    kB<<<NBLK_B, 256, 0, stream>>>(pc, keys, pA, W1, b1, g1, be1, cnt, pB, stats1);
    kS1<<<128, 256, 0, stream>>>(cnt, bsum, pB, W2, b2, g2, be2, stats2);
    kS2<<<128, 256, 0, stream>>>(cnt, bsum, startc, vi, nuni);
    kC<<<2048, 256, 0, stream>>>(pc, keys, cnt, pid, stats1, stats2, feat);
    kV<<<2048, 256, 0, stream>>>(feat, pid, startc, nuni, vf, vi);
}

// Round 8
// 191.339 us; speedup vs baseline: 2.1728x; 1.0221x over previous
//
#include <hip/hip_runtime.h>

typedef unsigned int u32;
typedef unsigned long long u64;

#define N_PTS 480000
#define PPB   120000      // points per batch (B=4)
#define NKEY  131072      // 4 * 32^3 compact key space
#define NBLK_A 256
#define NBLK_B 256
#define SLOPE 0.01f

// ================= node 1: zero cnt + keys + x-moment partials =================
__global__ __launch_bounds__(256) void kA0(const float* __restrict__ pc,
                                           const int* __restrict__ pidx,
                                           u32* __restrict__ keys,
                                           u32* __restrict__ cnt,
                                           float* __restrict__ pA) {
    int t = threadIdx.x;
    int g = blockIdx.x * 256 + t;
    ((u64*)cnt)[g] = 0ull;            // 65536 threads x 8B = 512KB, exact

    float a[14];
#pragma unroll
    for (int j = 0; j < 14; ++j) a[j] = 0.f;

    for (int n = g; n < N_PTS; n += NBLK_A * 256) {
        float4 x = ((const float4*)pc)[n];
        a[0] += x.x; a[1] += x.y; a[2] += x.z; a[3] += x.w;
        a[4] += x.x * x.x; a[5] += x.x * x.y; a[6]  += x.x * x.z; a[7]  += x.x * x.w;
        a[8] += x.y * x.y; a[9] += x.y * x.z; a[10] += x.y * x.w;
        a[11] += x.z * x.z; a[12] += x.z * x.w; a[13] += x.w * x.w;

        int i0 = pidx[3 * n], i1 = pidx[3 * n + 1], i2 = pidx[3 * n + 2];
        int bid = n / PPB;
        keys[n] = (u32)(bid * 32768 + i0 * 1024 + i1 * 32 + i2);
    }

    __shared__ float red[256];
    for (int j = 0; j < 14; ++j) {
        red[t] = a[j];
        __syncthreads();
        for (int s = 128; s > 0; s >>= 1) {
            if (t < s) red[t] += red[t + s];
            __syncthreads();
        }
        if (t == 0) pA[j * NBLK_A + blockIdx.x] = red[0];   // moment-major
        __syncthreads();
    }
}

// ================= node 2: fold1 (per block) + histogram + h-moments =================
__global__ __launch_bounds__(256, 1) void kB(const float* __restrict__ pc,
                                             const u32* __restrict__ keys,
                                             const float* __restrict__ pA,
                                             const float* __restrict__ W1,
                                             const float* __restrict__ b1,
                                             const float* __restrict__ g1,
                                             const float* __restrict__ be1,
                                             u32* __restrict__ cnt,
                                             float* __restrict__ pB,
                                             float* __restrict__ stats1) {
    int t = threadIdx.x, w = t >> 6, lane = t & 63;
    __shared__ float S[14];
    __shared__ float sW[80];
    __shared__ float sred[4][152];

    // fold1: reduce pA (every block, redundantly -- kills a launch)
    for (int q = w; q < 14; q += 4) {
        const float* p = pA + q * NBLK_A;
        float s = p[lane] + p[lane + 64] + p[lane + 128] + p[lane + 192];
        for (int d = 32; d > 0; d >>= 1) s += __shfl_xor(s, d);
        if (lane == 0) S[q] = s;
    }
    __syncthreads();
    if (t < 16) {
        int c = t;
        double w4[4];
#pragma unroll
        for (int i = 0; i < 4; ++i) w4[i] = W1[i * 16 + c];
        double sx[4] = { S[0], S[1], S[2], S[3] };
        auto sxx = [&](int i, int j) -> double {
            if (i > j) { int k = i; i = j; j = k; }
            int base = (i == 0) ? 4 : (i == 1) ? 8 : (i == 2) ? 11 : 13;
            return (double)S[base + (j - i)];
        };
        double su = 0.0;
        for (int i = 0; i < 4; ++i) su += sx[i] * w4[i];
        double q = 0.0;
        for (int i = 0; i < 4; ++i)
            for (int j = 0; j < 4; ++j) q += w4[i] * w4[j] * sxx(i, j);
        double b = (double)b1[c];
        double sum   = su + b * (double)N_PTS;
        double sumsq = q + 2.0 * b * su + (double)N_PTS * b * b;
        double mean = sum / (double)N_PTS;
        double var  = sumsq / (double)N_PTS - mean * mean;
        float inv = rsqrtf((float)(var + 1e-5));
        float sc = g1[c] * inv;
        float sf = be1[c] - (float)mean * sc;
#pragma unroll
        for (int i = 0; i < 4; ++i) sW[c * 4 + i] = W1[i * 16 + c] * sc;
        sW[64 + c] = b1[c] * sc + sf;
        if (blockIdx.x == 0) {
#pragma unroll
            for (int i = 0; i < 4; ++i) stats1[c * 4 + i] = sW[c * 4 + i];
            stats1[64 + c] = sW[64 + c];
        }
    }
    __syncthreads();

    // histogram (cnt zeroed by node 1)
    for (int n = blockIdx.x * 256 + t; n < N_PTS; n += NBLK_B * 256)
        atomicAdd(&cnt[keys[n]], 1u);

    // h-moments in registers
    float acc[152];
#pragma unroll
    for (int m = 0; m < 152; ++m) acc[m] = 0.f;

    const float4* sW4 = (const float4*)sW;
    for (int n = blockIdx.x * 256 + t; n < N_PTS; n += NBLK_B * 256) {
        float4 x = ((const float4*)pc)[n];
        float h[16];
#pragma unroll
        for (int k = 0; k < 16; ++k) {
            float4 wk = sW4[k];
            float z = x.x * wk.x + x.y * wk.y + x.z * wk.z + x.w * wk.w + sW[64 + k];
            h[k] = (z >= 0.f) ? z : SLOPE * z;
        }
#pragma unroll
        for (int i = 0; i < 16; ++i) acc[i] += h[i];
#pragma unroll
        for (int i = 0; i < 16; ++i)
#pragma unroll
            for (int j = i; j < 16; ++j)
                acc[16 + i * 16 - (i * (i - 1)) / 2 + (j - i)] += h[i] * h[j];
    }

#pragma unroll
    for (int m = 0; m < 152; ++m) {
        float s = acc[m];
        for (int d = 32; d > 0; d >>= 1) s += __shfl_xor(s, d);
        acc[m] = s;
    }
    if (lane == 0) {
#pragma unroll
        for (int m = 0; m < 152; ++m) sred[w][m] = acc[m];
    }
    __syncthreads();
    if (t < 152)
        pB[t * NBLK_B + blockIdx.x] = sred[0][t] + sred[1][t] + sred[2][t] + sred[3][t];
}

// ================= node 3: scan pass 1 (128 blocks) + fold2 in block 0 =================
__global__ __launch_bounds__(256) void kS1(const u32* __restrict__ cnt,
                                           u32* __restrict__ bsum,
                                           const float* __restrict__ pB,
                                           const float* __restrict__ W2,
                                           const float* __restrict__ b2,
                                           const float* __restrict__ g2,
                                           const float* __restrict__ be2,
                                           float* __restrict__ stats2) {
    int t = threadIdx.x, b = blockIdx.x;
    uint4 c4 = ((const uint4*)cnt)[b * 256 + t];
    u32 cs = c4.x + c4.y + c4.z + c4.w;
    u32 os = (c4.x > 0) + (c4.y > 0) + (c4.z > 0) + (c4.w > 0);
    __shared__ u32 rc[256], ro[256];
    rc[t] = cs; ro[t] = os;
    __syncthreads();
    for (int s = 128; s > 0; s >>= 1) {
        if (t < s) { rc[t] += rc[t + s]; ro[t] += ro[t + s]; }
        __syncthreads();
    }
    if (t == 0) { bsum[2 * b] = rc[0]; bsum[2 * b + 1] = ro[0]; }

    if (b == 0) {
        int w = t >> 6, lane = t & 63;
        __shared__ float S[152];
        for (int q = w; q < 152; q += 4) {
            const float* p = pB + q * NBLK_B;
            float s = p[lane] + p[lane + 64] + p[lane + 128] + p[lane + 192];
            for (int d = 32; d > 0; d >>= 1) s += __shfl_xor(s, d);
            if (lane == 0) S[q] = s;
        }
        __syncthreads();
        if (t < 64) {
            double wv[16];
#pragma unroll
            for (int k = 0; k < 16; ++k) wv[k] = W2[k * 64 + t];
            double sh = 0.0;
            for (int k = 0; k < 16; ++k) sh += wv[k] * (double)S[k];
            auto qidx = [&](int i, int j) { return 16 + i * 16 - (i * (i - 1)) / 2 + (j - i); };
            double q = 0.0;
            for (int i = 0; i < 16; ++i) {
                q += wv[i] * wv[i] * (double)S[qidx(i, i)];
                double t2 = 0.0;
                for (int j = i + 1; j < 16; ++j) t2 += wv[j] * (double)S[qidx(i, j)];
                q += 2.0 * wv[i] * t2;
            }
            double bb = (double)b2[t];
            double sum   = sh + bb * (double)N_PTS;
            double sumsq = q + 2.0 * bb * sh + (double)N_PTS * bb * bb;
            double mean = sum / (double)N_PTS;
            double var  = sumsq / (double)N_PTS - mean * mean;
            float inv = rsqrtf((float)(var + 1e-5));
            float scs = g2[t] * inv;
            float sf = be2[t] - (float)mean * scs;
#pragma unroll
            for (int k = 0; k < 16; ++k) stats2[k * 64 + t] = W2[k * 64 + t] * scs;
            stats2[1024 + t] = b2[t] * scs + sf;
        }
    }
}

// ================= node 4: scan pass 2: cursors, startc, vi rows, n_uni =================
__global__ __launch_bounds__(256) void kS2(u32* __restrict__ cnt,
                                           const u32* __restrict__ bsum,
                                           u32* __restrict__ startc,
                                           float* __restrict__ vi,
                                           u32* __restrict__ nuni) {
    int t = threadIdx.x, b = blockIdx.x;
    __shared__ u32 sbc[128], sbo[128];
    __shared__ u32 cOff, oOff;
    __shared__ u64 scan[256];
    if (t < 128) { sbc[t] = bsum[2 * t]; sbo[t] = bsum[2 * t + 1]; }

    uint4 c4 = ((const uint4*)cnt)[b * 256 + t];
    u32 cv[4] = { c4.x, c4.y, c4.z, c4.w };
    u32 cs = cv[0] + cv[1] + cv[2] + cv[3];
    u32 os = (cv[0] > 0) + (cv[1] > 0) + (cv[2] > 0) + (cv[3] > 0);
    scan[t] = ((u64)cs << 32) | (u64)os;
    __syncthreads();
    if (t == 0) {
        u32 a = 0, o = 0;
        for (int i = 0; i < b; ++i) { a += sbc[i]; o += sbo[i]; }
        cOff = a; oOff = o;
    }
    for (int d = 1; d < 256; d <<= 1) {
        u64 v = (t >= d) ? scan[t - d] : 0ull;
        __syncthreads();
        scan[t] += v;
        __syncthreads();
    }
    u64 ex = scan[t] - (((u64)cs << 32) | (u64)os);
    u32 start = cOff + (u32)(ex >> 32);
    u32 rank  = oOff + (u32)(ex & 0xffffffffull);

    int kbase = b * 1024 + t * 4;
#pragma unroll
    for (int j = 0; j < 4; ++j) {
        u32 k = (u32)(kbase + j);
        cnt[k] = start;                     // cursor
        if (cv[j] > 0) {
            startc[rank] = start;
            float4 o;
            o.x = (float)(k >> 15);
            o.y = (float)((k >> 10) & 31);
            o.z = (float)((k >> 5) & 31);
            o.w = (float)(k & 31);
            ((float4*)vi)[rank] = o;
            rank++;
        }
        start += cv[j];
    }
    if (b == 127 && t == 255) {
        nuni[0] = rank;
        startc[rank] = N_PTS;               // sentinel
    }
}

// ================= node 5: scatter point ids into voxel-sorted order =================
__global__ __launch_bounds__(256) void kP(const u32* __restrict__ keys,
                                          u32* __restrict__ cursor,
                                          u32* __restrict__ pid) {
    int n = blockIdx.x * 256 + threadIdx.x;
    if (n < N_PTS) {
        u32 k = keys[n];
        u32 pos = atomicAdd(&cursor[k], 1u);
        pid[pos] = (u32)n;
    }
}

// ================= node 6: voxel-ordered MLP recompute + feat + vf max + tails =================
__global__ __launch_bounds__(256) void kW(const float* __restrict__ pc,
                                          const u32* __restrict__ pid,
                                          const u32* __restrict__ startc,
                                          const u32* __restrict__ nuni,
                                          const float* __restrict__ stats1,
                                          const float* __restrict__ stats2,
                                          float* __restrict__ feat,
                                          float* __restrict__ vf,
                                          float* __restrict__ vi) {
    u32 nu = *nuni;
    int w = threadIdx.x >> 6, lane = threadIdx.x & 63;

    // layer-1 folded weights for this lane's h channel (lanes 0-15 are authoritative)
    int k1 = lane & 15;
    float w1c[4];
#pragma unroll
    for (int i = 0; i < 4; ++i) w1c[i] = stats1[k1 * 4 + i];
    float c1 = stats1[64 + k1];

    // layer-2 folded weights for this lane's output channel
    float w2c[16];
#pragma unroll
    for (int k = 0; k < 16; ++k) w2c[k] = stats2[k * 64 + lane];
    float c2f = stats2[1024 + lane];

    for (u32 r = blockIdx.x * 4 + (u32)w; r < N_PTS; r += 8192) {
        if (r < nu) {
            u32 s = startc[r], e = startc[r + 1];
            float m = -3.4e38f;
            for (u32 i = s; i < e; ++i) {
                u32 p = pid[i];
                float4 x = ((const float4*)pc)[p];
                float hk = x.x * w1c[0] + x.y * w1c[1] + x.z * w1c[2] + x.w * w1c[3] + c1;
                hk = (hk >= 0.f) ? hk : SLOPE * hk;
                u32 hbits = __float_as_uint(hk);
                float f = c2f;
#pragma unroll
                for (int k = 0; k < 16; ++k) {
                    float hv = __uint_as_float((u32)__builtin_amdgcn_readlane((int)hbits, k));
                    f += hv * w2c[k];
                }
                f = (f >= 0.f) ? f : SLOPE * f;
                feat[(size_t)p * 64 + lane] = f;
                m = fmaxf(m, f);
            }
            vf[(size_t)r * 64 + lane] = m;
        } else {
            vf[(size_t)r * 64 + lane] = 0.f;
            if (lane < 4) vi[(size_t)r * 4 + lane] = 0.f;
        }
    }
}

extern "C" void kernel_launch(void* const* d_in, const int* in_sizes, int n_in,
                              void* d_out, int out_size, void* d_ws, size_t ws_size,
                              hipStream_t stream) {
    const float* pc   = (const float*)d_in[0];
    const int*   pidx = (const int*)d_in[1];
    const float* W1   = (const float*)d_in[2];
    const float* b1   = (const float*)d_in[3];
    const float* g1   = (const float*)d_in[4];
    const float* be1  = (const float*)d_in[5];
    const float* W2   = (const float*)d_in[6];
    const float* b2   = (const float*)d_in[7];
    const float* g2   = (const float*)d_in[8];
    const float* be2  = (const float*)d_in[9];

    float* vf   = (float*)d_out;                    // [N,64]
    float* vi   = vf + (size_t)N_PTS * 64;          // [N,4]
    float* feat = vi + (size_t)N_PTS * 4;           // [N,64]

    u32* ws     = (u32*)d_ws;
    u32* keys   = ws;                        // 480000
    u32* cnt    = ws + 480000;               // 131072 (count -> cursor)
    u32* startc = ws + 611072;               // 131073 (+pad)
    u32* bsum   = ws + 742148;               // 256
    u32* nuni   = ws + 742404;               // 1 (+pad)
    u32* pid    = ws + 742420;               // 480000
    float* pA     = (float*)(ws + 1222420);  // 14*256 = 3584
    float* stats1 = (float*)(ws + 1226004);  // 80
    float* pB     = (float*)(ws + 1226084);  // 152*256 = 38912
    float* stats2 = (float*)(ws + 1264996);  // 1088

    kA0<<<NBLK_A, 256, 0, stream>>>(pc, pidx, keys, cnt, pA);
    kB<<<NBLK_B, 256, 0, stream>>>(pc, keys, pA, W1, b1, g1, be1, cnt, pB, stats1);
    kS1<<<128, 256, 0, stream>>>(cnt, bsum, pB, W2, b2, g2, be2, stats2);
    kS2<<<128, 256, 0, stream>>>(cnt, bsum, startc, vi, nuni);
    kP<<<1875, 256, 0, stream>>>(keys, cnt, pid);
    kW<<<2048, 256, 0, stream>>>(pc, pid, startc, nuni, stats1, stats2, feat, vf, vi);
}